// Round 14
// baseline (877.736 us; speedup 1.0000x reference)
//
#include <hip/hip_runtime.h>
#include <hip/hip_bf16.h>

// AWQ w4a16 GEMM + fused LoRA, MI355X (gfx950).
//   Xe  [8192][4160] bf16 = [ x (bf16) | t = x @ lora_a (bf16) ]
//   Wt  [11008][4160] bf16 = [ ((q - z) * s)^T | lora_b^T ]
//   out [8192][11008] f32 = Xe @ Wt^T     (K' = 4160, NT = 65 K-tiles of 64)
// r14: r12 GEMM pipeline factored into template<NTILES,ATOMIC> gemm_body.
// Tail-quantization fix: 1280 full tiles (bn 0-39, exactly 5 rounds) +
// 192 split-K blocks (bn 40-42, K halves 33/32) dispatched last ->
// makespan 6T -> ~5.5T. Split blocks atomicAdd; prep zeroes their stripe.

typedef __bf16 bf16x8 __attribute__((ext_vector_type(8)));
typedef float f32x16 __attribute__((ext_vector_type(16)));

#define GLOAD_LDS16(gp, lp)                                                    \
  __builtin_amdgcn_global_load_lds(                                            \
      (const __attribute__((address_space(1))) void*)(gp),                     \
      (__attribute__((address_space(3))) void*)(lp), 16, 0, 0)

#define SB0() __builtin_amdgcn_sched_barrier(0)
#define BAR() __builtin_amdgcn_s_barrier()

// T19: interleave R ds_reads and G vmem ops among the 8 MFMAs of a cluster.
#define ILV(R, G)                                                              \
  do {                                                                         \
    _Pragma("unroll") for (int ii = 0; ii < 8; ++ii) {                         \
      __builtin_amdgcn_sched_group_barrier(0x8, 1, 0);                         \
      if (ii < (R)) __builtin_amdgcn_sched_group_barrier(0x100, 1, 0);         \
      if (ii < (G)) __builtin_amdgcn_sched_group_barrier(0x10, 1, 0);          \
    }                                                                          \
  } while (0)

__device__ __forceinline__ unsigned short f2b(float f) {
  unsigned int u = __builtin_bit_cast(unsigned int, f);
  unsigned int r = u + 0x7fffu + ((u >> 16) & 1u);  // RTNE
  return (unsigned short)(r >> 16);
}

constexpr int M_DIM = 8192;
constexpr int K_DIM = 4096;
constexpr int N_DIM = 11008;
constexpr int R_DIM = 64;
constexpr int KP = K_DIM + R_DIM;  // 4160

constexpr int NPX = M_DIM / 16;                    // 512 prep_x blocks
constexpr int NDQ = (N_DIM / 256) * (K_DIM / 64);  // 2752 dequant blocks
constexpr int NLB = N_DIM / 64;                    // 172 lorab blocks
constexpr int NZR = M_DIM / 16;                    // 512 stripe-zero blocks

constexpr int NFULL = 40 * 32;   // 1280 full tiles (bn 0..39)
constexpr int NSPLIT = 96 * 2;   // 192 split-K blocks (bn 40..42)

// ---------------------------------------------------------------- merged prep
__global__ __launch_bounds__(256) void prep_all_kernel(
    const float* __restrict__ x, const float* __restrict__ A,
    const float* __restrict__ B, const int* __restrict__ qw,
    const int* __restrict__ qz, const float* __restrict__ sc,
    unsigned short* __restrict__ Xe, unsigned short* __restrict__ Wt,
    float* __restrict__ out) {
  __shared__ __align__(16) char smem[41088];
  const int bid = blockIdx.x;
  const int tid = threadIdx.x;

  if (bid < NPX) {
    // ---------------- prep_x: 16 rows of t = x@A, plus x->bf16 passthrough
    float (*xs)[128] = (float (*)[128])smem;
    float (*as)[64] = (float (*)[64])(smem + 8192);
    const int r0 = bid * 16;
    const int c = tid & 63;
    const int rg = tid >> 6;
    float acc[4] = {0.f, 0.f, 0.f, 0.f};
    for (int kc = 0; kc < K_DIM; kc += 128) {
      __syncthreads();
#pragma unroll
      for (int i = 0; i < 2; ++i) {
        const int flat = i * 1024 + tid * 4;
        const int row = flat >> 7, col = flat & 127;
        const float4 v =
            *(const float4*)(x + (size_t)(r0 + row) * K_DIM + kc + col);
        *(float4*)&xs[row][col] = v;
        unsigned short h[4] = {f2b(v.x), f2b(v.y), f2b(v.z), f2b(v.w)};
        *(uint2*)(Xe + (size_t)(r0 + row) * KP + kc + col) = *(const uint2*)h;
      }
#pragma unroll
      for (int j = 0; j < 8; ++j)
        ((float4*)as)[j * 256 + tid] =
            ((const float4*)(A + (size_t)kc * R_DIM))[j * 256 + tid];
      __syncthreads();
      for (int kk = 0; kk < 128; kk += 4) {
        float4 xv[4];
#pragma unroll
        for (int i = 0; i < 4; ++i) xv[i] = *(const float4*)&xs[rg * 4 + i][kk];
#pragma unroll
        for (int q = 0; q < 4; ++q) {
          const float b = as[kk + q][c];
          acc[0] += ((const float*)&xv[0])[q] * b;
          acc[1] += ((const float*)&xv[1])[q] * b;
          acc[2] += ((const float*)&xv[2])[q] * b;
          acc[3] += ((const float*)&xv[3])[q] * b;
        }
      }
    }
#pragma unroll
    for (int i = 0; i < 4; ++i)
      Xe[(size_t)(r0 + rg * 4 + i) * KP + K_DIM + c] = f2b(acc[i]);

  } else if (bid < NPX + NDQ) {
    // ---------------- dequant + transpose, tile 64k x 256n
    unsigned short (*w_lds)[257] = (unsigned short (*)[257])smem;
    const int i2 = bid - NPX;
    const int n0 = (i2 % (N_DIM / 256)) * 256;
    const int k0 = (i2 / (N_DIM / 256)) * 64;
    const int g = k0 >> 7;
    const int nl = (tid & 63) * 4;
    const int kb = tid >> 6;
    const int4 zq = *(const int4*)(qz + (size_t)g * N_DIM + n0 + nl);
    const float4 sv = *(const float4*)(sc + (size_t)g * N_DIM + n0 + nl);
#pragma unroll
    for (int i = 0; i < 16; ++i) {
      const int kl = i * 4 + kb;
      const int4 q = *(const int4*)(qw + (size_t)(k0 + kl) * N_DIM + n0 + nl);
      w_lds[kl][nl + 0] = f2b((float)(q.x - zq.x) * sv.x);
      w_lds[kl][nl + 1] = f2b((float)(q.y - zq.y) * sv.y);
      w_lds[kl][nl + 2] = f2b((float)(q.z - zq.z) * sv.z);
      w_lds[kl][nl + 3] = f2b((float)(q.w - zq.w) * sv.w);
    }
    __syncthreads();
    const int c = tid & 7;
    const int ns = (tid >> 3) & 7;
    const int w = tid >> 6;
#pragma unroll
    for (int v = 0; v < 8; ++v) {
      const int n = w * 64 + v * 8 + ns;
      unsigned short tmp[8];
#pragma unroll
      for (int i = 0; i < 8; ++i) tmp[i] = w_lds[c * 8 + i][n];
      *(uint4*)(Wt + (size_t)(n0 + n) * KP + k0 + c * 8) = *(const uint4*)tmp;
    }

  } else if (bid < NPX + NDQ + NLB) {
    // ---------------- lora_b^T into Wt cols [4096, 4160)
    unsigned short (*b_lds)[68] = (unsigned short (*)[68])smem;
    const int n0 = (bid - NPX - NDQ) * 64;
    const int nl = tid & 63;
    const int rl0 = tid >> 6;
#pragma unroll
    for (int i = 0; i < 16; ++i) {
      const int rl = i * 4 + rl0;
      b_lds[nl][rl] = f2b(B[(size_t)rl * N_DIM + n0 + nl]);
    }
    __syncthreads();
#pragma unroll
    for (int p = 0; p < 2; ++p) {
      const int chunk = p * 256 + tid;
      const int nr = chunk >> 3, r8 = chunk & 7;
      const unsigned short* rp = &b_lds[nr][r8 * 8];
      const uint2 lo = *(const uint2*)rp;
      const uint2 hi = *(const uint2*)(rp + 4);
      uint4 v;
      v.x = lo.x; v.y = lo.y; v.z = hi.x; v.w = hi.y;
      *(uint4*)(Wt + (size_t)(n0 + nr) * KP + K_DIM + r8 * 8) = v;
    }

  } else {
    // ---------------- zero out[:, 10240:11008) for split-K atomic accumulation
    const int r0 = (bid - NPX - NDQ - NLB) * 16;
    const float4 z = {0.f, 0.f, 0.f, 0.f};
#pragma unroll
    for (int i = 0; i < 12; ++i) {
      const int flat = i * 256 + tid;           // 16 rows x 192 f4
      const int row = flat / 192, c4 = flat % 192;
      *(float4*)(out + (size_t)(r0 + row) * N_DIM + 10240 + c4 * 4) = z;
    }
  }
}

// ---------------------------------------------------------------- GEMM body (r12 pipeline)
#define LGKM0() do { asm volatile("s_waitcnt lgkmcnt(0)" ::: "memory"); SB0(); } while (0)
#define PRIO_ON()  __builtin_amdgcn_s_setprio(1)
#define PRIO_OFF() __builtin_amdgcn_s_setprio(0)
#define VM4() asm volatile("s_waitcnt vmcnt(4)" ::: "memory")
#define VM2() asm volatile("s_waitcnt vmcnt(2)" ::: "memory")
#define VM0() asm volatile("s_waitcnt vmcnt(0)" ::: "memory")
#define VNOP() ((void)0)

template <int NTILES, bool ATOMIC>
__device__ __forceinline__ void gemm_body(
    const unsigned short* __restrict__ Xe, const unsigned short* __restrict__ Wt,
    float* __restrict__ out, int bm, int bn, int beg,
    unsigned short (*lds)[2][2][128 * 64]) {
  const int tid = threadIdx.x;
  const int w = tid >> 6, lane = tid & 63;
  const int wr = w >> 2, wc = w & 3;

  // staging: lane l writes phys chunk (l&7) of stripe-row w*8+(l>>3); source
  // logical chunk = (l&7) ^ sigma(row), sigma(row) = (row&7)^((row>>3)&3)
  const int rb = w * 8 + (lane >> 3);
  const int sc = ((lane & 7) ^ (lane >> 3) ^ (w & 3)) * 8;
  const unsigned short* gA = Xe + (size_t)(bm * 256 + rb) * KP + sc + beg * 64;
  const unsigned short* gB = Wt + (size_t)(bn * 256 + rb) * KP + sc + beg * 64;

  const int rowA32 = (lane & 31) * 64;
  const int rowB32 = ((wc & 1) * 64 + (lane & 31)) * 64;
  int cxk[4];
#pragma unroll
  for (int ks = 0; ks < 4; ++ks)
    cxk[ks] = ((ks * 2 + (lane >> 5)) ^ (lane & 7) ^ ((lane >> 3) & 3)) * 8;

  f32x16 acc[4][2];
#pragma unroll
  for (int i = 0; i < 4; ++i)
#pragma unroll
    for (int j = 0; j < 2; ++j) acc[i][j] = (f32x16)0.f;

  bf16x8 a[2][4], b0x[4], b0y[4], b1[4];

  auto stage1 = [&](const unsigned short* g, int buf, int op, int half, int rq,
                    int kt) {
    const unsigned short* s = g + (size_t)(half * 128 + rq * 64) * KP + kt * 64;
    unsigned short* d = &lds[buf][op][half][rq * 4096 + w * 512];
    GLOAD_LDS16(s, d);
  };

#define LDA(BUF, mh)                                                           \
  do {                                                                         \
    const unsigned short* R = &lds[BUF][0][wr][0];                             \
    _Pragma("unroll") for (int i = 0; i < 2; ++i)                              \
    _Pragma("unroll") for (int ks = 0; ks < 4; ++ks)                           \
      a[i][ks] =                                                               \
          *(const bf16x8*)(R + ((mh)*2 + i) * 2048 + rowA32 + cxk[ks]);        \
  } while (0)

#define LDB(BUF, dst, nh)                                                      \
  do {                                                                         \
    const unsigned short* R = &lds[BUF][1][wc >> 1][0];                        \
    _Pragma("unroll") for (int ks = 0; ks < 4; ++ks)                           \
      dst[ks] = *(const bf16x8*)(R + (nh)*2048 + rowB32 + cxk[ks]);            \
  } while (0)

#define MFMAQ(mh, bb, nh)                                                      \
  do {                                                                         \
    _Pragma("unroll") for (int ks = 0; ks < 4; ++ks)                           \
    _Pragma("unroll") for (int i = 0; i < 2; ++i)                              \
      acc[(mh)*2 + i][nh] = __builtin_amdgcn_mfma_f32_32x32x16_bf16(           \
          a[i][ks], bb[ks], acc[(mh)*2 + i][nh], 0, 0, 0);                     \
  } while (0)

#define TILE(KT, BUF, CURB, NXTB, S1, S2, VMA, VMB, LAST)                      \
  do {                                                                         \
    const int kt_ = (KT);                                                      \
    /* I1: 8 MFMA | 4 ds_read | 2 vmem */                                      \
    LGKM0();                                                                   \
    PRIO_ON(); MFMAQ(0, CURB, 0);                                              \
    LDB(BUF, b1, 1);                                                           \
    PRIO_OFF();                                                                \
    if (S1) { stage1(gA, (BUF) ^ 1, 0, 0, 0, kt_ + 1);                         \
              stage1(gA, (BUF) ^ 1, 0, 1, 0, kt_ + 1); }                       \
    ILV(4, (S1) ? 2 : 0);                                                      \
    SB0(); BAR(); SB0();                                                       \
    /* I2: 8 MFMA | 8 ds_read | 2 vmem */                                      \
    LGKM0();                                                                   \
    PRIO_ON(); MFMAQ(0, b1, 1);                                                \
    LDA(BUF, 1);                                                               \
    PRIO_OFF();                                                                \
    if (S1) { stage1(gA, (BUF) ^ 1, 0, 0, 1, kt_ + 1);                         \
              stage1(gA, (BUF) ^ 1, 0, 1, 1, kt_ + 1); }                       \
    ILV(8, (S1) ? 2 : 0);                                                      \
    SB0(); VMA(); SB0(); BAR(); SB0();                                         \
    /* I3: 8 MFMA | 4 ds_read | 2 vmem */                                      \
    LGKM0();                                                                   \
    PRIO_ON(); MFMAQ(1, b1, 1);                                                \
    if (!(LAST)) { LDB((BUF) ^ 1, NXTB, 0); }                                  \
    PRIO_OFF();                                                                \
    if (S2) { stage1(gB, (BUF), 1, 0, 0, kt_ + 2);                             \
              stage1(gB, (BUF), 1, 1, 0, kt_ + 2); }                           \
    ILV((LAST) ? 0 : 4, (S2) ? 2 : 0);                                         \
    SB0(); VMB(); SB0(); BAR(); SB0();                                         \
    /* I4: 8 MFMA | 8 ds_read | 2 vmem */                                      \
    LGKM0();                                                                   \
    PRIO_ON(); MFMAQ(1, CURB, 0);                                              \
    if (!(LAST)) { LDA((BUF) ^ 1, 0); }                                        \
    PRIO_OFF();                                                                \
    if (S2) { stage1(gB, (BUF), 1, 0, 1, kt_ + 2);                             \
              stage1(gB, (BUF), 1, 1, 1, kt_ + 2); }                           \
    ILV((LAST) ? 0 : 8, (S2) ? 2 : 0);                                         \
    SB0(); BAR(); SB0();                                                       \
  } while (0)

  // prologue: stage tile0 A+B, tile1 B; vmcnt(4); initial fragment reads
  stage1(gA, 0, 0, 0, 0, 0); stage1(gA, 0, 0, 1, 0, 0);
  stage1(gA, 0, 0, 0, 1, 0); stage1(gA, 0, 0, 1, 1, 0);
  stage1(gB, 0, 1, 0, 0, 0); stage1(gB, 0, 1, 1, 0, 0);
  stage1(gB, 0, 1, 0, 1, 0); stage1(gB, 0, 1, 1, 1, 0);
  stage1(gB, 1, 1, 0, 0, 1); stage1(gB, 1, 1, 1, 0, 1);
  stage1(gB, 1, 1, 0, 1, 1); stage1(gB, 1, 1, 1, 1, 1);
  SB0(); VM4(); SB0(); BAR(); SB0();
  LDA(0, 0);
  LDB(0, b0x, 0);

  if constexpr (NTILES & 1) {
#pragma unroll 1
    for (int kt = 0; kt < NTILES - 3; kt += 2) {
      TILE(kt,     0, b0x, b0y, true, true, VM4, VM2, false);
      TILE(kt + 1, 1, b0y, b0x, true, true, VM4, VM2, false);
    }
    TILE(NTILES - 3, 0, b0x, b0y, true,  true,  VM4,  VM2,  false);
    TILE(NTILES - 2, 1, b0y, b0x, true,  false, VM4,  VM0,  false);
    TILE(NTILES - 1, 0, b0x, b0y, false, false, VNOP, VNOP, true);
  } else {
#pragma unroll 1
    for (int kt = 0; kt < NTILES - 4; kt += 2) {
      TILE(kt,     0, b0x, b0y, true, true, VM4, VM2, false);
      TILE(kt + 1, 1, b0y, b0x, true, true, VM4, VM2, false);
    }
    TILE(NTILES - 4, 0, b0x, b0y, true,  true,  VM4,  VM2,  false);
    TILE(NTILES - 3, 1, b0y, b0x, true,  true,  VM4,  VM2,  false);
    TILE(NTILES - 2, 0, b0x, b0y, true,  false, VM4,  VM0,  false);
    TILE(NTILES - 1, 1, b0y, b0x, false, false, VNOP, VNOP, true);
  }

  // epilogue: 32x32 C/D: col = lane&31, row = (reg&3)+8*(reg>>2)+4*(lane>>5)
  const int orow = bm * 256 + wr * 128 + ((lane >> 5) << 2);
  const int ocol = bn * 256 + wc * 64 + (lane & 31);
#pragma unroll
  for (int mf = 0; mf < 4; ++mf)
#pragma unroll
    for (int nf = 0; nf < 2; ++nf)
#pragma unroll
      for (int reg = 0; reg < 16; ++reg) {
        const size_t idx =
            (size_t)(orow + mf * 32 + (reg & 3) + ((reg >> 2) << 3)) * N_DIM +
            ocol + nf * 32;
        if constexpr (ATOMIC) atomicAdd(&out[idx], acc[mf][nf][reg]);
        else out[idx] = acc[mf][nf][reg];
      }
}

// ---------------------------------------------------------------- main GEMM
__global__ __launch_bounds__(512, 2) void gemm_kernel(
    const unsigned short* __restrict__ Xe, const unsigned short* __restrict__ Wt,
    float* __restrict__ out) {
  __shared__ unsigned short lds[2][2][2][128 * 64];
  const int orig = blockIdx.x;
  if (orig < NFULL) {
    // full tiles, bn 0..39; XCD swizzle within segment: 1280 = 8 * 160
    const int wg = (orig & 7) * 160 + (orig >> 3);
    const int bm = wg & 31;
    const int bn = wg >> 5;
    gemm_body<65, false>(Xe, Wt, out, bm, bn, 0, lds);
  } else {
    // split-K blocks, bn 40..42, dispatched last; 192 = 8 * 24
    const int o2 = orig - NFULL;
    const int wg2 = (o2 & 7) * 24 + (o2 >> 3);
    const int t = wg2 >> 1, half = wg2 & 1;
    const int bm = t & 31;
    const int bn = 40 + (t >> 5);
    if (half == 0) gemm_body<33, true>(Xe, Wt, out, bm, bn, 0, lds);
    else           gemm_body<32, true>(Xe, Wt, out, bm, bn, 33, lds);
  }
}

// ---------------------------------------------------------------- launch
extern "C" void kernel_launch(void* const* d_in, const int* in_sizes, int n_in,
                              void* d_out, int out_size, void* d_ws, size_t ws_size,
                              hipStream_t stream) {
  const float* x = (const float*)d_in[0];
  const float* scales = (const float*)d_in[1];
  const float* lora_a = (const float*)d_in[2];
  const float* lora_b = (const float*)d_in[3];
  const int* qweight = (const int*)d_in[4];
  const int* qzeros = (const int*)d_in[5];
  float* out = (float*)d_out;

  unsigned short* Xe = (unsigned short*)d_ws;
  unsigned short* Wt = Xe + (size_t)M_DIM * KP;

  prep_all_kernel<<<NPX + NDQ + NLB + NZR, 256, 0, stream>>>(
      x, lora_a, lora_b, qweight, qzeros, scales, Xe, Wt, out);
  gemm_kernel<<<NFULL + NSPLIT, 512, 0, stream>>>(Xe, Wt, out);
}

// Round 15
// 854.804 us; speedup vs baseline: 1.0268x; 1.0268x over previous
//
#include <hip/hip_runtime.h>
#include <hip/hip_bf16.h>

// AWQ w4a16 GEMM + fused LoRA, MI355X (gfx950).
//   Xe  [8192][4160] bf16 = [ x (bf16) | t = x @ lora_a (bf16) ]
//   Wt  [11008][4160] bf16 = [ ((q - z) * s)^T | lora_b^T ]
//   out [8192][11008] f32 = Xe @ Wt^T     (K' = 4160, NT = 65 K-tiles of 64)
// r15 = r13 exact revert (measured best: 852 us total). r14's split-K tail
// fix regressed (makespan model wrong; atomic+zero overhead real) — removed.
// GEMM: 256x256, 8 waves 2Mx4N, BK=64, 128 KiB LDS, 32x32x16 MFMA,
// sigma(row)=(row&7)^((row>>3)&3) swizzle both sides (0 conflicts),
// 4 intervals/K-tile with reads pipelined one interval ahead, counted
// vmcnt(4)/(2), T19 sched_group_barrier MFMA||ds_read||vmem interleave,
// setprio around MFMA. Prep: single merged kernel (prep_x | dequant | lorab).

typedef __bf16 bf16x8 __attribute__((ext_vector_type(8)));
typedef float f32x16 __attribute__((ext_vector_type(16)));

#define GLOAD_LDS16(gp, lp)                                                    \
  __builtin_amdgcn_global_load_lds(                                            \
      (const __attribute__((address_space(1))) void*)(gp),                     \
      (__attribute__((address_space(3))) void*)(lp), 16, 0, 0)

#define SB0() __builtin_amdgcn_sched_barrier(0)
#define BAR() __builtin_amdgcn_s_barrier()

// T19: interleave R ds_reads and G vmem ops among the 8 MFMAs of a cluster.
#define ILV(R, G)                                                              \
  do {                                                                         \
    _Pragma("unroll") for (int ii = 0; ii < 8; ++ii) {                         \
      __builtin_amdgcn_sched_group_barrier(0x8, 1, 0);                         \
      if (ii < (R)) __builtin_amdgcn_sched_group_barrier(0x100, 1, 0);         \
      if (ii < (G)) __builtin_amdgcn_sched_group_barrier(0x10, 1, 0);          \
    }                                                                          \
  } while (0)

__device__ __forceinline__ unsigned short f2b(float f) {
  unsigned int u = __builtin_bit_cast(unsigned int, f);
  unsigned int r = u + 0x7fffu + ((u >> 16) & 1u);  // RTNE
  return (unsigned short)(r >> 16);
}

constexpr int M_DIM = 8192;
constexpr int K_DIM = 4096;
constexpr int N_DIM = 11008;
constexpr int R_DIM = 64;
constexpr int KP = K_DIM + R_DIM;  // 4160
constexpr int NT = KP / 64;        // 65 K-tiles

constexpr int NPX = M_DIM / 16;                    // 512 prep_x blocks
constexpr int NDQ = (N_DIM / 256) * (K_DIM / 64);  // 2752 dequant blocks
constexpr int NLB = N_DIM / 64;                    // 172 lorab blocks

// ---------------------------------------------------------------- merged prep
// blocks [0, NPX): prep_x (t = x@A + x->bf16). FMA-bound, longest -> first.
// blocks [NPX, NPX+NDQ): dequant+transpose.  blocks [NPX+NDQ, +NLB): lorab^T.
__global__ __launch_bounds__(256) void prep_all_kernel(
    const float* __restrict__ x, const float* __restrict__ A,
    const float* __restrict__ B, const int* __restrict__ qw,
    const int* __restrict__ qz, const float* __restrict__ sc,
    unsigned short* __restrict__ Xe, unsigned short* __restrict__ Wt) {
  __shared__ __align__(16) char smem[41088];
  const int bid = blockIdx.x;
  const int tid = threadIdx.x;

  if (bid < NPX) {
    // ---------------- prep_x: 16 rows of t = x@A, plus x->bf16 passthrough
    float (*xs)[128] = (float (*)[128])smem;              // 16x128 f32, 8 KB
    float (*as)[64] = (float (*)[64])(smem + 8192);       // 128x64 f32, 32 KB
    const int r0 = bid * 16;
    const int c = tid & 63;
    const int rg = tid >> 6;
    float acc[4] = {0.f, 0.f, 0.f, 0.f};
    for (int kc = 0; kc < K_DIM; kc += 128) {
      __syncthreads();
#pragma unroll
      for (int i = 0; i < 2; ++i) {
        const int flat = i * 1024 + tid * 4;
        const int row = flat >> 7, col = flat & 127;
        const float4 v =
            *(const float4*)(x + (size_t)(r0 + row) * K_DIM + kc + col);
        *(float4*)&xs[row][col] = v;
        unsigned short h[4] = {f2b(v.x), f2b(v.y), f2b(v.z), f2b(v.w)};
        *(uint2*)(Xe + (size_t)(r0 + row) * KP + kc + col) = *(const uint2*)h;
      }
#pragma unroll
      for (int j = 0; j < 8; ++j)
        ((float4*)as)[j * 256 + tid] =
            ((const float4*)(A + (size_t)kc * R_DIM))[j * 256 + tid];
      __syncthreads();
      for (int kk = 0; kk < 128; kk += 4) {
        float4 xv[4];
#pragma unroll
        for (int i = 0; i < 4; ++i) xv[i] = *(const float4*)&xs[rg * 4 + i][kk];
#pragma unroll
        for (int q = 0; q < 4; ++q) {
          const float b = as[kk + q][c];
          acc[0] += ((const float*)&xv[0])[q] * b;
          acc[1] += ((const float*)&xv[1])[q] * b;
          acc[2] += ((const float*)&xv[2])[q] * b;
          acc[3] += ((const float*)&xv[3])[q] * b;
        }
      }
    }
#pragma unroll
    for (int i = 0; i < 4; ++i)
      Xe[(size_t)(r0 + rg * 4 + i) * KP + K_DIM + c] = f2b(acc[i]);

  } else if (bid < NPX + NDQ) {
    // ---------------- dequant + transpose, tile 64k x 256n
    unsigned short (*w_lds)[257] = (unsigned short (*)[257])smem;  // 32.9 KB
    const int i2 = bid - NPX;
    const int n0 = (i2 % (N_DIM / 256)) * 256;
    const int k0 = (i2 / (N_DIM / 256)) * 64;
    const int g = k0 >> 7;  // 64-k tile never crosses a 128-k group
    const int nl = (tid & 63) * 4;
    const int kb = tid >> 6;
    const int4 zq = *(const int4*)(qz + (size_t)g * N_DIM + n0 + nl);
    const float4 sv = *(const float4*)(sc + (size_t)g * N_DIM + n0 + nl);
#pragma unroll
    for (int i = 0; i < 16; ++i) {
      const int kl = i * 4 + kb;
      const int4 q = *(const int4*)(qw + (size_t)(k0 + kl) * N_DIM + n0 + nl);
      w_lds[kl][nl + 0] = f2b((float)(q.x - zq.x) * sv.x);
      w_lds[kl][nl + 1] = f2b((float)(q.y - zq.y) * sv.y);
      w_lds[kl][nl + 2] = f2b((float)(q.z - zq.z) * sv.z);
      w_lds[kl][nl + 3] = f2b((float)(q.w - zq.w) * sv.w);
    }
    __syncthreads();
    const int c = tid & 7;          // k-chunk (8 k = 16B)
    const int ns = (tid >> 3) & 7;  // n-sub within wave
    const int w = tid >> 6;
#pragma unroll
    for (int v = 0; v < 8; ++v) {
      const int n = w * 64 + v * 8 + ns;
      unsigned short tmp[8];
#pragma unroll
      for (int i = 0; i < 8; ++i) tmp[i] = w_lds[c * 8 + i][n];
      *(uint4*)(Wt + (size_t)(n0 + n) * KP + k0 + c * 8) = *(const uint4*)tmp;
    }

  } else {
    // ---------------- lora_b^T into Wt cols [4096, 4160)
    unsigned short (*b_lds)[68] = (unsigned short (*)[68])smem;  // 8.7 KB
    const int n0 = (bid - NPX - NDQ) * 64;
    const int nl = tid & 63;
    const int rl0 = tid >> 6;
#pragma unroll
    for (int i = 0; i < 16; ++i) {
      const int rl = i * 4 + rl0;
      b_lds[nl][rl] = f2b(B[(size_t)rl * N_DIM + n0 + nl]);
    }
    __syncthreads();
#pragma unroll
    for (int p = 0; p < 2; ++p) {
      const int chunk = p * 256 + tid;
      const int nr = chunk >> 3, r8 = chunk & 7;
      const unsigned short* rp = &b_lds[nr][r8 * 8];
      const uint2 lo = *(const uint2*)rp;
      const uint2 hi = *(const uint2*)(rp + 4);
      uint4 v;
      v.x = lo.x; v.y = lo.y; v.z = hi.x; v.w = hi.y;
      *(uint4*)(Wt + (size_t)(n0 + nr) * KP + K_DIM + r8 * 8) = v;
    }
  }
}

// ---------------------------------------------------------------- main GEMM (r12, unchanged)
__global__ __launch_bounds__(512, 2) void gemm_kernel(
    const unsigned short* __restrict__ Xe, const unsigned short* __restrict__ Wt,
    float* __restrict__ out) {
  __shared__ unsigned short lds[2][2][2][128 * 64];
  const int tid = threadIdx.x;
  const int w = tid >> 6, lane = tid & 63;
  // T1: bijective XCD swizzle, 1376 = 8 * 172
  const int orig = blockIdx.x;
  const int wg = (orig & 7) * 172 + (orig >> 3);
  const int bm = wg & 31;   // 32 M-tiles
  const int bn = wg >> 5;   // 43 N-tiles
  const int wr = w >> 2, wc = w & 3;

  // staging: lane l writes phys chunk (l&7) of stripe-row w*8+(l>>3); source
  // logical chunk = (l&7) ^ sigma(row), sigma(row) = (row&7)^((row>>3)&3)
  const int rb = w * 8 + (lane >> 3);
  const int sc = ((lane & 7) ^ (lane >> 3) ^ (w & 3)) * 8;
  const unsigned short* gA = Xe + (size_t)(bm * 256 + rb) * KP + sc;
  const unsigned short* gB = Wt + (size_t)(bn * 256 + rb) * KP + sc;

  // fragment reads: row r = l&31 (+32 multiples), phys chunk =
  // logical ^ (l&7) ^ ((l>>3)&3) -- bank-spread (r7-verified, 0 conflicts)
  const int rowA32 = (lane & 31) * 64;
  const int rowB32 = ((wc & 1) * 64 + (lane & 31)) * 64;
  int cxk[4];
#pragma unroll
  for (int ks = 0; ks < 4; ++ks)
    cxk[ks] = ((ks * 2 + (lane >> 5)) ^ (lane & 7) ^ ((lane >> 3) & 3)) * 8;

  f32x16 acc[4][2];
#pragma unroll
  for (int i = 0; i < 4; ++i)
#pragma unroll
    for (int j = 0; j < 2; ++j) acc[i][j] = (f32x16)0.f;

  bf16x8 a[2][4], b0x[4], b0y[4], b1[4];

  // one gload_lds: rows [rq*64, rq*64+64) of region [op][half]
  auto stage1 = [&](const unsigned short* g, int buf, int op, int half, int rq,
                    int kt) {
    const unsigned short* s = g + (size_t)(half * 128 + rq * 64) * KP + kt * 64;
    unsigned short* d = &lds[buf][op][half][rq * 4096 + w * 512];
    GLOAD_LDS16(s, d);
  };

#define LDA(BUF, mh)                                                           \
  do {                                                                         \
    const unsigned short* R = &lds[BUF][0][wr][0];                             \
    _Pragma("unroll") for (int i = 0; i < 2; ++i)                              \
    _Pragma("unroll") for (int ks = 0; ks < 4; ++ks)                           \
      a[i][ks] =                                                               \
          *(const bf16x8*)(R + ((mh)*2 + i) * 2048 + rowA32 + cxk[ks]);        \
  } while (0)

#define LDB(BUF, dst, nh)                                                      \
  do {                                                                         \
    const unsigned short* R = &lds[BUF][1][wc >> 1][0];                        \
    _Pragma("unroll") for (int ks = 0; ks < 4; ++ks)                           \
      dst[ks] = *(const bf16x8*)(R + (nh)*2048 + rowB32 + cxk[ks]);            \
  } while (0)

#define MFMAQ(mh, bb, nh)                                                      \
  do {                                                                         \
    _Pragma("unroll") for (int ks = 0; ks < 4; ++ks)                           \
    _Pragma("unroll") for (int i = 0; i < 2; ++i)                              \
      acc[(mh)*2 + i][nh] = __builtin_amdgcn_mfma_f32_32x32x16_bf16(           \
          a[i][ks], bb[ks], acc[(mh)*2 + i][nh], 0, 0, 0);                     \
  } while (0)

#define LGKM0() do { asm volatile("s_waitcnt lgkmcnt(0)" ::: "memory"); SB0(); } while (0)
#define PRIO_ON()  __builtin_amdgcn_s_setprio(1)
#define PRIO_OFF() __builtin_amdgcn_s_setprio(0)
#define VM4() asm volatile("s_waitcnt vmcnt(4)" ::: "memory")
#define VM2() asm volatile("s_waitcnt vmcnt(2)" ::: "memory")
#define VM0() asm volatile("s_waitcnt vmcnt(0)" ::: "memory")
#define VNOP() ((void)0)

#define TILE(KT, BUF, CURB, NXTB, S1, S2, VMA, VMB, LAST)                      \
  do {                                                                         \
    const int kt_ = (KT);                                                      \
    /* I1: 8 MFMA | 4 ds_read | 2 vmem */                                      \
    LGKM0();                                                                   \
    PRIO_ON(); MFMAQ(0, CURB, 0);                                              \
    LDB(BUF, b1, 1);                                                           \
    PRIO_OFF();                                                                \
    if (S1) { stage1(gA, (BUF) ^ 1, 0, 0, 0, kt_ + 1);                         \
              stage1(gA, (BUF) ^ 1, 0, 1, 0, kt_ + 1); }                       \
    ILV(4, (S1) ? 2 : 0);                                                      \
    SB0(); BAR(); SB0();                                                       \
    /* I2: 8 MFMA | 8 ds_read | 2 vmem */                                      \
    LGKM0();                                                                   \
    PRIO_ON(); MFMAQ(0, b1, 1);                                                \
    LDA(BUF, 1);                                                               \
    PRIO_OFF();                                                                \
    if (S1) { stage1(gA, (BUF) ^ 1, 0, 0, 1, kt_ + 1);                         \
              stage1(gA, (BUF) ^ 1, 0, 1, 1, kt_ + 1); }                       \
    ILV(8, (S1) ? 2 : 0);                                                      \
    SB0(); VMA(); SB0(); BAR(); SB0();                                         \
    /* I3: 8 MFMA | 4 ds_read | 2 vmem */                                      \
    LGKM0();                                                                   \
    PRIO_ON(); MFMAQ(1, b1, 1);                                                \
    if (!(LAST)) { LDB((BUF) ^ 1, NXTB, 0); }                                  \
    PRIO_OFF();                                                                \
    if (S2) { stage1(gB, (BUF), 1, 0, 0, kt_ + 2);                             \
              stage1(gB, (BUF), 1, 1, 0, kt_ + 2); }                           \
    ILV((LAST) ? 0 : 4, (S2) ? 2 : 0);                                         \
    SB0(); VMB(); SB0(); BAR(); SB0();                                         \
    /* I4: 8 MFMA | 8 ds_read | 2 vmem */                                      \
    LGKM0();                                                                   \
    PRIO_ON(); MFMAQ(1, CURB, 0);                                              \
    if (!(LAST)) { LDA((BUF) ^ 1, 0); }                                        \
    PRIO_OFF();                                                                \
    if (S2) { stage1(gB, (BUF), 1, 0, 1, kt_ + 2);                             \
              stage1(gB, (BUF), 1, 1, 1, kt_ + 2); }                           \
    ILV((LAST) ? 0 : 8, (S2) ? 2 : 0);                                         \
    SB0(); BAR(); SB0();                                                       \
  } while (0)

  // prologue: stage A(0) q0,q1 (4), B(0) (4), B(1) (4); vmcnt(4) -> tile0
  // landed, B(1) in flight; then initial fragment reads.
  stage1(gA, 0, 0, 0, 0, 0); stage1(gA, 0, 0, 1, 0, 0);
  stage1(gA, 0, 0, 0, 1, 0); stage1(gA, 0, 0, 1, 1, 0);
  stage1(gB, 0, 1, 0, 0, 0); stage1(gB, 0, 1, 1, 0, 0);
  stage1(gB, 0, 1, 0, 1, 0); stage1(gB, 0, 1, 1, 1, 0);
  stage1(gB, 1, 1, 0, 0, 1); stage1(gB, 1, 1, 1, 0, 1);
  stage1(gB, 1, 1, 0, 1, 1); stage1(gB, 1, 1, 1, 1, 1);
  SB0(); VM4(); SB0(); BAR(); SB0();
  LDA(0, 0);          // a = mh0(0)
  LDB(0, b0x, 0);     // b0x = B(0) n0   (awaited by tile0 I1's LGKM0)

#pragma unroll 1
  for (int kt = 0; kt < 62; kt += 2) {
    TILE(kt,     0, b0x, b0y, true, true, VM4, VM2, false);
    TILE(kt + 1, 1, b0y, b0x, true, true, VM4, VM2, false);
  }
  TILE(62, 0, b0x, b0y, true,  true,  VM4,  VM2,  false);
  TILE(63, 1, b0y, b0x, true,  false, VM4,  VM0,  false);
  TILE(64, 0, b0x, b0y, false, false, VNOP, VNOP, true);

  // epilogue: 32x32 C/D layout: col = lane&31, row = (reg&3)+8*(reg>>2)+4*(lane>>5)
  const int orow = bm * 256 + wr * 128 + ((lane >> 5) << 2);
  const int ocol = bn * 256 + wc * 64 + (lane & 31);
#pragma unroll
  for (int mf = 0; mf < 4; ++mf)
#pragma unroll
    for (int nf = 0; nf < 2; ++nf)
#pragma unroll
      for (int reg = 0; reg < 16; ++reg)
        out[(size_t)(orow + mf * 32 + (reg & 3) + ((reg >> 2) << 3)) * N_DIM +
            ocol + nf * 32] = acc[mf][nf][reg];
}

// ---------------------------------------------------------------- launch
extern "C" void kernel_launch(void* const* d_in, const int* in_sizes, int n_in,
                              void* d_out, int out_size, void* d_ws, size_t ws_size,
                              hipStream_t stream) {
  const float* x = (const float*)d_in[0];
  const float* scales = (const float*)d_in[1];
  const float* lora_a = (const float*)d_in[2];
  const float* lora_b = (const float*)d_in[3];
  const int* qweight = (const int*)d_in[4];
  const int* qzeros = (const int*)d_in[5];
  float* out = (float*)d_out;

  unsigned short* Xe = (unsigned short*)d_ws;
  unsigned short* Wt = Xe + (size_t)M_DIM * KP;

  prep_all_kernel<<<NPX + NDQ + NLB, 256, 0, stream>>>(
      x, lora_a, lora_b, qweight, qzeros, scales, Xe, Wt);
  gemm_kernel<<<dim3((N_DIM / 256) * (M_DIM / 256)), 512, 0, stream>>>(Xe, Wt, out);
}